// Round 6
// baseline (51.880 us; speedup 1.0000x reference)
//
#include <hip/hip_runtime.h>
#include <math.h>

// diag-RTRL, round 6: round-4 split-K structure, PLAIN stores, ILP-8 E-stream.
//   s      = tanh(0.9*u + x@W)         [32,1024]
//   u_new  = 0.9*u + x@W               [32,1024]
//   E_new  = 0.9*E + x[:,:,None]       [32,1024,1024]  (268 MB stream, dominates)
//
// Round-5 post-mortem: sc1|nt inline-asm stores CORRUPTED read-back (stale
// zeroed L2 lines served validation: absmax 5.86 = max|x|). Streaming-store
// cache hints are unusable for harness-visible outputs on gfx950, and plain
// `nt` (builtin) never reduced FETCH anyway (70 vs 68 MB). Lever dead.
// This round: plain f4 stores (hypothesis: nt was HURTING write combining in
// L2; plain stores allocate+combine+lazy writeback) and 8-wide load ILP.
// Everything else identical to round 4 (48.6 us, passed).

#define BETA 0.9f

constexpr int Bb   = 32;
constexpr int D_IN = 1024;
constexpr int D_H  = 1024;

constexpr int THREADS    = 256;
constexpr int KSPLIT     = 32;                 // 32 k-chunks of 32 rows
constexpr int JTILES     = 16;                 // 16 j-tiles of 64 cols
constexpr int GEMM_TILES = KSPLIT * JTILES;    // 512 blocks carry a tile
constexpr int GRID1      = 2048;
constexpr int TRIPS_G    = 13;                 // E trips for tile-carrying blocks
constexpr int TRIPS_E    = 17;                 // E trips for plain blocks
// 512*13 + 1536*17 = 32768 trips * 256 f4 = 8,388,608 f4 = full E.

typedef float f4 __attribute__((ext_vector_type(4)));

__global__ __launch_bounds__(THREADS) void rtrl_k1(
    const float* __restrict__ x,   // [32,1024]
    const float* __restrict__ W,   // [1024,1024]
    const float* __restrict__ E,   // [32,1024,1024]
    float* __restrict__ out,       // [s | u_new | E_new]
    float* __restrict__ ws)        // [KSPLIT][32][1024] partials
{
    __shared__ float Wt[32][64];   // 8 KB  : k-chunk x j-tile of W
    __shared__ float xs[32][32];   // 4 KB  : all b x k-chunk of x

    const int blk = blockIdx.x;
    const int tid = threadIdx.x;

    if (blk < GEMM_TILES) {
        // ---------- one GEMM tile: kt = k-chunk, jt = j-tile ----------
        const int kt = blk >> 4;          // 0..31
        const int jt = blk & 15;          // 0..15
        const int i0 = kt * 32;
        const int j0 = jt * 64;

        const f4* __restrict__ W4 = (const f4*)W;   // row stride 256 f4
        const f4* __restrict__ x4 = (const f4*)x;   // row stride 256 f4

        // load W tile: 32 rows x 16 f4 = 512 f4, 2 per thread
        {
            f4* Wt4 = (f4*)Wt;
            #pragma unroll
            for (int p = 0; p < 2; ++p) {
                const int idx = tid + p * 256;
                const int row = idx >> 4, c4 = idx & 15;
                Wt4[row * 16 + c4] = W4[(i0 + row) * 256 + (j0 >> 2) + c4];
            }
        }
        // load x tile: 32 b x 8 f4 = 256 f4, 1 per thread
        {
            f4* xs4 = (f4*)xs;
            const int row = tid >> 3, c4 = tid & 7;
            xs4[row * 8 + c4] = x4[row * 256 + (i0 >> 2) + c4];
        }
        __syncthreads();

        // compute: each thread -> 8 batch rows, one j column
        const int bg = tid >> 6;          // wave-uniform: 8-batch group
        const int jc = tid & 63;          // column within tile
        float a0=0,a1=0,a2=0,a3=0,a4=0,a5=0,a6=0,a7=0;
        #pragma unroll 8
        for (int i = 0; i < 32; ++i) {
            const float wv = Wt[i][jc];   // 64 consecutive lanes: conflict-free
            a0 = fmaf(xs[bg*8+0][i], wv, a0);  // xs reads broadcast (uniform addr)
            a1 = fmaf(xs[bg*8+1][i], wv, a1);
            a2 = fmaf(xs[bg*8+2][i], wv, a2);
            a3 = fmaf(xs[bg*8+3][i], wv, a3);
            a4 = fmaf(xs[bg*8+4][i], wv, a4);
            a5 = fmaf(xs[bg*8+5][i], wv, a5);
            a6 = fmaf(xs[bg*8+6][i], wv, a6);
            a7 = fmaf(xs[bg*8+7][i], wv, a7);
        }
        float acc[8] = {a0,a1,a2,a3,a4,a5,a6,a7};
        #pragma unroll
        for (int bb = 0; bb < 8; ++bb) {
            const int b = bg * 8 + bb;
            ws[(kt * Bb + b) * D_H + j0 + jc] = acc[bb];   // coalesced
        }
    }

    // ---------- E stream: contiguous region per block, ILP-8 ----------
    const f4* __restrict__ E4 = (const f4*)E;
    f4* __restrict__ O4 = (f4*)(out + 2 * Bb * D_H);

    const int ntrips = (blk < GEMM_TILES) ? TRIPS_G : TRIPS_E;
    const int r0     = (blk < GEMM_TILES)
                     ? blk * (TRIPS_G * THREADS)
                     : GEMM_TILES * (TRIPS_G * THREADS) + (blk - GEMM_TILES) * (TRIPS_E * THREADS);

    int v = r0 + tid;
    int t = 0;
    for (; t + 8 <= ntrips; t += 8) {     // 8 loads in flight
        f4    e[8];
        float xv[8];
        #pragma unroll
        for (int j = 0; j < 8; ++j) e[j]  = E4[v + j * 256];
        #pragma unroll
        for (int j = 0; j < 8; ++j) xv[j] = x[(v + j * 256) >> 8];
        #pragma unroll
        for (int j = 0; j < 8; ++j) O4[v + j * 256] = e[j] * BETA + xv[j];
        v += 8 * 256;
    }
    for (; t + 4 <= ntrips; t += 4) {
        f4    e[4];
        float xv[4];
        #pragma unroll
        for (int j = 0; j < 4; ++j) e[j]  = E4[v + j * 256];
        #pragma unroll
        for (int j = 0; j < 4; ++j) xv[j] = x[(v + j * 256) >> 8];
        #pragma unroll
        for (int j = 0; j < 4; ++j) O4[v + j * 256] = e[j] * BETA + xv[j];
        v += 4 * 256;
    }
    for (; t < ntrips; ++t) {
        f4 e = E4[v];
        const float xv = x[v >> 8];
        O4[v] = e * BETA + xv;
        v += 256;
    }
}

__global__ __launch_bounds__(THREADS) void rtrl_k2(
    const float* __restrict__ ws,  // [KSPLIT][32][1024]
    const float* __restrict__ u,   // [32,1024]
    float* __restrict__ out)       // [s | u_new | ...]
{
    const int t = blockIdx.x * THREADS + threadIdx.x;   // output (b,j), 32768 total
    float acc = 0.f;
    #pragma unroll
    for (int k = 0; k < KSPLIT; ++k)
        acc += ws[k * (Bb * D_H) + t];                  // coalesced, L2/L3-resident
    const float un = BETA * u[t] + acc;
    out[t]            = tanhf(un);   // s
    out[Bb * D_H + t] = un;          // u_new
}

extern "C" void kernel_launch(void* const* d_in, const int* in_sizes, int n_in,
                              void* d_out, int out_size, void* d_ws, size_t ws_size,
                              hipStream_t stream) {
    const float* x = (const float*)d_in[0];
    const float* W = (const float*)d_in[1];
    const float* u = (const float*)d_in[2];
    const float* E = (const float*)d_in[3];
    float* out = (float*)d_out;
    float* ws  = (float*)d_ws;     // needs KSPLIT*32*1024*4 = 4 MB

    rtrl_k1<<<GRID1, THREADS, 0, stream>>>(x, W, E, out, ws);
    rtrl_k2<<<(Bb * D_H) / THREADS, THREADS, 0, stream>>>(ws, u, out);
}